// Round 6
// baseline (800.302 us; speedup 1.0000x reference)
//
#include <hip/hip_runtime.h>
#include <cstdint>
#include <cstddef>

typedef unsigned short u16;
typedef __attribute__((ext_vector_type(8))) short bf16x8;   // 8 bf16 = 4 VGPRs
typedef __attribute__((ext_vector_type(4))) float f32x4;    // MFMA accumulator

#define DEVFN static __device__ __forceinline__

DEVFN u16 f2bf(float f) {
  unsigned u = __float_as_uint(f);
  unsigned r = (u + 0x7FFFu + ((u >> 16) & 1u)) >> 16;   // RTN-even
  return (u16)r;
}

// async global->LDS, 16B/lane. LDS dest = wave-uniform base + lane*16 (m104/m108).
DEVFN void gload16(const void* g, void* l) {
  __builtin_amdgcn_global_load_lds(
      (const __attribute__((address_space(1))) void*)g,
      (__attribute__((address_space(3))) void*)l, 16, 0, 0);
}

// ---------------- merged prep: converts + wqkv row-permute + cos/sin table ----------------
// wqkv q/k rows interleaved per head: d<64 -> 2d, d>=64 -> 2(d-64)+1  (QK^T invariant).
// cs[l*64+m] = (cos(l,m), sin(l,m))
__global__ void prep(const float* __restrict__ x, const float* __restrict__ wqkv,
                     const float* __restrict__ wout, const float* __restrict__ cosp,
                     const float* __restrict__ sinp, u16* __restrict__ xb,
                     u16* __restrict__ wqkvb, u16* __restrict__ woutb,
                     float2* __restrict__ cs) {
  constexpr int X4 = 4194304;      // x elems/4
  constexpr int W4 = 3145728;      // wqkv elems/4
  constexpr int O4 = 1048576;      // wout elems/4
  int i = blockIdx.x * blockDim.x + threadIdx.x;
  if (i < X4) {
    float4 v = ((const float4*)x)[i];
    unsigned long long w = (unsigned long long)f2bf(v.x)
        | ((unsigned long long)f2bf(v.y) << 16)
        | ((unsigned long long)f2bf(v.z) << 32)
        | ((unsigned long long)f2bf(v.w) << 48);
    *(unsigned long long*)(xb + (size_t)i * 4) = w;
  } else if (i < X4 + W4) {
    int j = i - X4;
    int base = j * 4;
    int e = base >> 11, col = base & 2047;
    int e2;
    if (e < 4096) {
      int part = e >> 11, loc = e & 2047;
      int h = loc >> 7, d = loc & 127;
      int d2 = (d < 64) ? 2 * d : 2 * (d - 64) + 1;
      e2 = part * 2048 + h * 128 + d2;
    } else {
      e2 = e;                      // v rows unpermuted
    }
    float4 v = *(const float4*)&wqkv[(size_t)base];
    unsigned long long w = (unsigned long long)f2bf(v.x)
        | ((unsigned long long)f2bf(v.y) << 16)
        | ((unsigned long long)f2bf(v.z) << 32)
        | ((unsigned long long)f2bf(v.w) << 48);
    *(unsigned long long*)(wqkvb + (size_t)e2 * 2048 + col) = w;
  } else if (i < X4 + W4 + O4) {
    int j = i - X4 - W4;
    float4 v = ((const float4*)wout)[j];
    unsigned long long w = (unsigned long long)f2bf(v.x)
        | ((unsigned long long)f2bf(v.y) << 16)
        | ((unsigned long long)f2bf(v.z) << 32)
        | ((unsigned long long)f2bf(v.w) << 48);
    *(unsigned long long*)(woutb + (size_t)j * 4) = w;
  } else {
    int k = i - X4 - W4 - O4;      // < 32768
    int ld4 = k * 4;
#pragma unroll
    for (int u = 0; u < 4; u++) {
      int ld = ld4 + u;
      int l = ld >> 6, d = ld & 63;
      cs[ld] = make_float2(cosp[(size_t)l * 128 + d], sinp[(size_t)l * 128 + d]);
    }
  }
}

// ---------------- bf16 GEMM core: C[M,N] = A[M,K] * Bt[N,K]^T, fused epilogues ----------------
// 128x128 tile, BK=32, 4 waves (2x2), wave 64x64 (4x4 MFMA). m97 staging via gload16,
// unpadded LDS rows + chunk XOR swizzle -> 2-way bank alias only (free, m136).
enum { M_F32OUT = 0, M_ROPE = 1, M_VT = 2 };

template <int MODE>
DEVFN void gemm_core(const u16* __restrict__ A, const u16* __restrict__ Bt,
                     void* __restrict__ Cv, const float2* __restrict__ cs,
                     int N, int K, int m0, int n0, u16* As, u16* Bs) {
  int tid = threadIdx.x;
  int wv = tid >> 6, lane = tid & 63, quad = lane >> 4, l16 = lane & 15;
  int wm = (wv >> 1) * 64, wn = (wv & 1) * 64;
  f32x4 acc[4][4] = {};
  int r0 = wv * 16 + (lane >> 2);
  int r1 = r0 + 64;
  int c0 = (lane & 3) ^ ((r0 >> 1) & 3);
  int c1 = (lane & 3) ^ ((r1 >> 1) & 3);
  const u16* Ap0 = A + (size_t)(m0 + r0) * K + c0 * 8;
  const u16* Ap1 = A + (size_t)(m0 + r1) * K + c1 * 8;
  const u16* Bp0 = Bt + (size_t)(n0 + r0) * K + c0 * 8;
  const u16* Bp1 = Bt + (size_t)(n0 + r1) * K + c1 * 8;
  u16* As0 = &As[(wv * 16) * 32];
  u16* As1 = &As[(wv * 16 + 64) * 32];
  u16* Bs0 = &Bs[(wv * 16) * 32];
  u16* Bs1 = &Bs[(wv * 16 + 64) * 32];
  for (int k0 = 0; k0 < K; k0 += 32) {
    __syncthreads();
    gload16(Ap0, As0);
    gload16(Ap1, As1);
    gload16(Bp0, Bs0);
    gload16(Bp1, Bs1);
    Ap0 += 32; Ap1 += 32; Bp0 += 32; Bp1 += 32;
    __syncthreads();
    bf16x8 af[4], bf[4];
#pragma unroll
    for (int i = 0; i < 4; i++) {
      int r = wm + i * 16 + l16;
      af[i] = *(const bf16x8*)&As[r * 32 + ((quad ^ ((r >> 1) & 3)) << 3)];
    }
#pragma unroll
    for (int j = 0; j < 4; j++) {
      int r = wn + j * 16 + l16;
      bf[j] = *(const bf16x8*)&Bs[r * 32 + ((quad ^ ((r >> 1) & 3)) << 3)];
    }
#pragma unroll
    for (int i = 0; i < 4; i++)
#pragma unroll
      for (int j = 0; j < 4; j++) {
        if (MODE == M_VT)
          acc[i][j] = __builtin_amdgcn_mfma_f32_16x16x32_bf16(bf[j], af[i], acc[i][j], 0, 0, 0);
        else
          acc[i][j] = __builtin_amdgcn_mfma_f32_16x16x32_bf16(af[i], bf[j], acc[i][j], 0, 0, 0);
      }
  }
  // C/D layout: col = lane&15, row = quad*4 + reg  (m89/m91 verified)
  if (MODE == M_F32OUT) {
    float* C = (float*)Cv;
#pragma unroll
    for (int i = 0; i < 4; i++)
#pragma unroll
      for (int r = 0; r < 4; r++) {
        size_t row = (size_t)(m0 + wm + i * 16 + quad * 4 + r);
#pragma unroll
        for (int j = 0; j < 4; j++)
          C[row * N + (n0 + wn + j * 16 + l16)] = acc[i][j][r];
      }
  } else if (MODE == M_ROPE) {
    constexpr float QSCALE = 1.4426950408889634f * 0.08838834764831845f;
    const float scale = (n0 >> 11) ? 1.0f : QSCALE;   // q gets log2e/sqrt(128)
    u16* C = (u16*)Cv;
#pragma unroll
    for (int i = 0; i < 4; i++)
#pragma unroll
      for (int r = 0; r < 4; r++) {
        int row = m0 + wm + i * 16 + quad * 4 + r;
        int l = row & 2047;
#pragma unroll
        for (int j = 0; j < 4; j++) {
          int col = n0 + wn + j * 16 + l16;
          int dm = (col & 127) >> 1;
          float2 csv = cs[l * 64 + dm];
          float v = acc[i][j][r];
          float pv = __shfl_xor(v, 1);                 // partner lane (col^1)
          float sg = (l16 & 1) ? csv.y : -csv.y;       // even: -sin, odd: +sin
          C[(size_t)row * 4096 + col] = f2bf((v * csv.x + pv * sg) * scale);
        }
      }
  } else {
    // VT: acc holds C^T tiles; row = v-channel, col = token. Store vt[bh][d][l].
    u16* vt = (u16*)Cv;
#pragma unroll
    for (int j = 0; j < 4; j++)
#pragma unroll
      for (int r = 0; r < 4; r++) {
        int vch = n0 + wn + j * 16 + quad * 4 + r;     // 0..2047
        int h = vch >> 7, d = vch & 127;
#pragma unroll
        for (int i = 0; i < 4; i++) {
          int token = m0 + wm + i * 16 + l16;
          int b = token >> 11, lloc = token & 2047;
          vt[((size_t)(b * 16 + h)) * 262144 + (size_t)d * 2048 + lloc] =
              f2bf(acc[i][j][r]);
        }
      }
  }
}

// Merged QKV GEMM: bx<32 -> RoPE epilogue into qkv (stride 4096); bx>=32 -> V^T.
// 1-D grid with XCD y-striping: each XCD owns an 8-row stripe of M (A rows L2-resident).
__global__ __launch_bounds__(256) void gemm_qkv(const u16* __restrict__ xb,
                                                const u16* __restrict__ wqkvb,
                                                u16* __restrict__ qkvo,
                                                u16* __restrict__ vto,
                                                const float2* __restrict__ cs) {
  __shared__ u16 As[128 * 32];
  __shared__ u16 Bs[128 * 32];
  int id = blockIdx.x;
  int xcd = id & 7, sub = id >> 3;      // sub 0..383
  int bx = sub % 48, by = xcd * 8 + sub / 48;
  if (bx < 32)
    gemm_core<M_ROPE>(xb, wqkvb, qkvo, cs, 0, 2048, by * 128, bx * 128, As, Bs);
  else
    gemm_core<M_VT>(xb, wqkvb + (size_t)4096 * 2048, vto, nullptr, 0, 2048,
                    by * 128, (bx - 32) * 128, As, Bs);
}

__global__ __launch_bounds__(256) void gemm_out_k(const u16* __restrict__ A,
                                                  const u16* __restrict__ Bt,
                                                  float* __restrict__ C) {
  __shared__ u16 As[128 * 32];
  __shared__ u16 Bs[128 * 32];
  int id = blockIdx.x;
  int xcd = id & 7, sub = id >> 3;      // sub 0..127
  int bx = sub % 16, by = xcd * 8 + sub / 16;
  gemm_core<M_F32OUT>(A, Bt, C, nullptr, 2048, 2048, by * 128, bx * 128, As, Bs);
}

// ---------------- fused flash attention v3: 2-D wave split + LDS double buffer ----------------
// 512 thr = 8 waves arranged 4(M: 32 q-rows) x 2(N: 32 keys of a 64-key tile).
// S-phase: each wave reads only its 32-key K slice (was: every wave read all 128 keys).
// P (128x64) round-trips through the dead K buffer; PV re-splits waves as 4(M) x 2(64 dims)
// with full key depth -> no cross-wave O reduce; l merges once in epilogue.
// Per-lane LDS reads per 128 keys: 40 vs 68 in R5 -> floor ~100 us.
// Double-buffered 64-key K/V tiles (4x16KB = 64KB); prefetch issued right after the
// staging-drain barrier so S-phase covers L2 latency (matters at 1 blk/CU).
// launch_bounds(512,2): VGPR cap 256 -> spill impossible (R4 lesson). ~115 regs expected.
DEVFN int swz16(int row, int chunk) { return row * 128 + ((chunk ^ (row & 15)) << 3); }
DEVFN int swz8(int row, int chunk) { return row * 64 + ((chunk ^ (row & 7)) << 3); }

__global__ __launch_bounds__(512, 2) void attn_fused(const u16* __restrict__ qkv,
                                                     const u16* __restrict__ vt,
                                                     u16* __restrict__ out) {
  __shared__ u16 Ksm[2][64 * 128];   // [buf][key][dim]; also Qsm(128x128) pre-loop, Psm(128x64) in-loop
  __shared__ u16 Vsm[2][128 * 64];   // [buf][dim][key]; also l-merge buffer in epilogue
  int tid = threadIdx.x;
  int wv = tid >> 6, lane = tid & 63, quad = lane >> 4, l16 = lane & 15;
  int mw = wv & 3, nw = wv >> 2;     // 4 x 2 wave grid
  int id = blockIdx.x;
  int xcd = id & 7, sub = id >> 3;             // sub 0..127
  int bh = ((sub >> 4) << 3) | xcd;            // 8 bh per XCD, all 16 qtiles local
  int qt = sub & 15;
  int b = bh >> 4, h = bh & 15;
  const u16* qptr = qkv + (size_t)b * 2048 * 4096 + h * 128;
  const u16* kptr = qptr + 2048;
  const u16* vptr = vt + (size_t)bh * 262144;
  int q0 = qt * 128;

  // ---- stage Q (128x128) through Ksm[0..1], pull A-fragments ----
  u16* Qsm = &Ksm[0][0];
#pragma unroll
  for (int j = 0; j < 4; j++) {
    int rb = wv * 4 + j * 32;
    int r = rb + (lane >> 4);
    int ck = (lane & 15) ^ (r & 15);
    gload16(&qptr[(size_t)(q0 + r) * 4096 + ck * 8], &Qsm[rb * 128]);
  }
  __syncthreads();
  bf16x8 qf[2][4];
#pragma unroll
  for (int m2 = 0; m2 < 2; m2++)
#pragma unroll
    for (int ks = 0; ks < 4; ks++)
      qf[m2][ks] = *(const bf16x8*)&Qsm[swz16(mw * 32 + m2 * 16 + l16, ks * 4 + quad)];
  __syncthreads();                   // all waves done with Q; Ksm reusable

  // ---- staging helper: 64-key K/V tile kt -> buf ----
  auto stage = [&](int kt, int buf) {
    int kk0 = kt * 64;
#pragma unroll
    for (int j = 0; j < 2; j++) {    // K: 64 rows x 128 dims
      int rb = wv * 4 + j * 32;
      int r = rb + (lane >> 4);
      int ck = (lane & 15) ^ (r & 15);
      gload16(&kptr[(size_t)(kk0 + r) * 4096 + ck * 8], &Ksm[buf][rb * 128]);
    }
#pragma unroll
    for (int j = 0; j < 2; j++) {    // V^T: 128 dim-rows x 64 keys
      int rb = wv * 8 + j * 64;
      int r = rb + (lane >> 3);
      int ck = (lane & 7) ^ (r & 7);
      gload16(&vptr[(size_t)r * 2048 + kk0 + ck * 8], &Vsm[buf][rb * 64]);
    }
  };
  stage(0, 0);

  f32x4 o[2][4] = {};                // [m2][ntd] : 32 q-rows x 64 dims
  float l[2][4] = {};

  for (int kt = 0; kt < 32; kt++) {
    int cur = kt & 1;
    __syncthreads();                 // staging(cur) drained; prior-iter LDS reads done
    if (kt + 1 < 32) stage(kt + 1, cur ^ 1);   // prefetch overlaps S-phase
    // S = Q K^T on this wave's 32-key slice (log2 domain: QSCALE folded into q)
    f32x4 s[2][2] = {};
#pragma unroll
    for (int ks = 0; ks < 4; ks++)
#pragma unroll
      for (int nt = 0; nt < 2; nt++) {
        bf16x8 kf = *(const bf16x8*)&Ksm[cur][swz16(nw * 32 + nt * 16 + l16, ks * 4 + quad)];
        s[0][nt] = __builtin_amdgcn_mfma_f32_16x16x32_bf16(qf[0][ks], kf, s[0][nt], 0, 0, 0);
        s[1][nt] = __builtin_amdgcn_mfma_f32_16x16x32_bf16(qf[1][ks], kf, s[1][nt], 0, 0, 0);
      }
    // fixed-base softmax: p = exp2(s); lane-local row sums
#pragma unroll
    for (int m2 = 0; m2 < 2; m2++)
#pragma unroll
      for (int nt = 0; nt < 2; nt++)
#pragma unroll
        for (int r = 0; r < 4; r++) {
          float p = exp2f(s[m2][nt][r]);
          s[m2][nt][r] = p;
          l[m2][r] += p;
        }
    __syncthreads();                 // all waves done reading K slices
    // P (C-layout) -> Psm = Ksm[cur] as [128 rows][64 keys], A-operand layout
    u16* Psm = &Ksm[cur][0];
#pragma unroll
    for (int m2 = 0; m2 < 2; m2++)
#pragma unroll
      for (int nt = 0; nt < 2; nt++) {
        int col = nw * 32 + nt * 16 + l16;
#pragma unroll
        for (int r = 0; r < 4; r++) {
          int row = mw * 32 + m2 * 16 + quad * 4 + r;
          unsigned hw = f2bf(s[m2][nt][r]);
          unsigned hp = (unsigned)__shfl_xor((int)hw, 1);
          if (!(l16 & 1))
            *(unsigned*)&Psm[swz8(row, col >> 3) + (col & 7)] = hw | (hp << 16);
        }
      }
    __syncthreads();                 // P complete
    // O += P V : full 64-key depth, this wave's 64-dim slice
#pragma unroll
    for (int ks2 = 0; ks2 < 2; ks2++) {
      bf16x8 pf0 = *(const bf16x8*)&Psm[swz8(mw * 32 + l16, ks2 * 4 + quad)];
      bf16x8 pf1 = *(const bf16x8*)&Psm[swz8(mw * 32 + 16 + l16, ks2 * 4 + quad)];
#pragma unroll
      for (int ntd = 0; ntd < 4; ntd++) {
        bf16x8 vf = *(const bf16x8*)&Vsm[cur][swz8(nw * 64 + ntd * 16 + l16, ks2 * 4 + quad)];
        o[0][ntd] = __builtin_amdgcn_mfma_f32_16x16x32_bf16(pf0, vf, o[0][ntd], 0, 0, 0);
        o[1][ntd] = __builtin_amdgcn_mfma_f32_16x16x32_bf16(pf1, vf, o[1][ntd], 0, 0, 0);
      }
    }
  }

  // ---- epilogue: merge l across 16 lanes + the two N-waves, divide, store ----
#pragma unroll
  for (int m2 = 0; m2 < 2; m2++)
#pragma unroll
    for (int r = 0; r < 4; r++)
#pragma unroll
      for (int off = 1; off < 16; off <<= 1)
        l[m2][r] += __shfl_xor(l[m2][r], off, 16);
  __syncthreads();                   // last PV reads done; reuse Vsm as l-buffer
  float* lbuf = (float*)&Vsm[0][0];  // [2][128]
  if (l16 == 0) {
#pragma unroll
    for (int m2 = 0; m2 < 2; m2++)
#pragma unroll
      for (int r = 0; r < 4; r++)
        lbuf[nw * 128 + mw * 32 + m2 * 16 + quad * 4 + r] = l[m2][r];
  }
  __syncthreads();
  u16* obase = out + ((size_t)b * 2048 + q0) * 2048 + h * 128;
#pragma unroll
  for (int m2 = 0; m2 < 2; m2++)
#pragma unroll
    for (int r = 0; r < 4; r++) {
      int row = mw * 32 + m2 * 16 + quad * 4 + r;
      float inv = 1.0f / (lbuf[row] + lbuf[128 + row]);
#pragma unroll
      for (int ntd = 0; ntd < 4; ntd++)
        obase[(size_t)row * 2048 + nw * 64 + ntd * 16 + l16] = f2bf(o[m2][ntd][r] * inv);
    }
}

// ---------------- launch ----------------
extern "C" void kernel_launch(void* const* d_in, const int* in_sizes, int n_in,
                              void* d_out, int out_size, void* d_ws, size_t ws_size,
                              hipStream_t stream) {
  const float* x    = (const float*)d_in[0];   // [4,2048,2048]
  const float* cosp = (const float*)d_in[1];   // [2048,128]
  const float* sinp = (const float*)d_in[2];   // [2048,128]
  const float* wqkv = (const float*)d_in[3];   // [6144,2048]
  const float* wout = (const float*)d_in[4];   // [2048,2048]
  float* outp = (float*)d_out;                 // [4,2048,2048] fp32

  u16* ws    = (u16*)d_ws;
  u16* xb    = ws;                     // 16,777,216 elems (dead after gemm_qkv; reused)
  u16* wqkvb = xb + 16777216;          // 12,582,912 (row-permuted q/k)
  u16* woutb = wqkvb + 12582912;       //  4,194,304
  u16* qkv   = woutb + 4194304;        // 33,554,432 (q,k only; row stride 4096)
  u16* vt    = qkv + 33554432;         // 16,777,216
  float2* cs = (float2*)(vt + 16777216); // 131,072 float2 = 1 MB
  u16* attn  = xb;                     // alias: xb dead after gemm_qkv

  prep<<<32896, 256, 0, stream>>>(x, wqkv, wout, cosp, sinp, xb, wqkvb, woutb, cs);
  gemm_qkv<<<3072, 256, 0, stream>>>(xb, wqkvb, qkv, vt, cs);
  attn_fused<<<1024, 512, 0, stream>>>(qkv, vt, attn);
  gemm_out_k<<<1024, 256, 0, stream>>>(attn, woutb, outp);
}